// Round 7
// baseline (527.729 us; speedup 1.0000x reference)
//
#include <hip/hip_runtime.h>
#include <stdint.h>

#define N_NODES 100000
#define N_EDGES 3200000
#define N_REL   16
#define NBKT    391         // ceil(100000/256) buckets of 256 nodes (bucket = src >> 8)
#define NBLK    128         // partition blocks; 3.2M/128 = 25000 edges each
#define EPB     25000
// EMB=32, N_CLS=50, BATCH=1024

typedef __attribute__((ext_vector_type(8))) short  short8;
typedef __attribute__((ext_vector_type(4))) short  short4_t;
typedef __attribute__((ext_vector_type(4))) float  f32x4;

static __device__ __forceinline__ unsigned short f32_to_bf16(float f) {
    union { float f; unsigned int u; } v; v.f = f;
    unsigned int u = v.u;
    unsigned int r = u + 0x7FFFu + ((u >> 16) & 1u);   // RNE
    return (unsigned short)(r >> 16);
}
static __device__ __forceinline__ float bf2f(unsigned short s) {
    union { unsigned int u; float f; } cv; cv.u = ((unsigned int)s) << 16;
    return cv.f;
}

// ---------------- emb0 f32 -> bf16 table (6.4 MB, L2/L3-resident gather target) --------
__global__ void k_embcast(const float* __restrict__ emb0, unsigned short* __restrict__ embbf) {
    int t = blockIdx.x * 256 + threadIdx.x;          // 3125 x 256 = 800000 = 3.2M/4
    f32x4 v = ((const f32x4*)emb0)[t];
    short4_t o;
#pragma unroll
    for (int e = 0; e < 4; ++e) o[e] = (short)f32_to_bf16(v[e]);
    ((short4_t*)embbf)[t] = o;
}

// ---------------- WcatT[i][k] = bf16(W1[k>>5][i][k&31]),  32 x 512 ----------------
__global__ void k_wcast(const float* __restrict__ W1, unsigned short* __restrict__ WcatT) {
    for (int t = threadIdx.x; t < 32 * 512; t += 512) {
        int i = t >> 9, k = t & 511;
        WcatT[t] = f32_to_bf16(W1[(size_t)(k >> 5) * 1024 + i * 32 + (k & 31)]);
    }
}

// ---------------- phase A: per-block bucket histogram (LDS atomics only) ----------------
__global__ __launch_bounds__(256) void k_histA(const int* __restrict__ src,
                                               int* __restrict__ table) {
    __shared__ int lh[NBKT];
    int tid = threadIdx.x, bid = blockIdx.x;
    for (int t = tid; t < NBKT; t += 256) lh[t] = 0;
    __syncthreads();
    int e0 = bid * EPB;
    for (int e = e0 + tid; e < e0 + EPB; e += 256)
        atomicAdd(&lh[src[e] >> 8], 1);
    __syncthreads();
    for (int t = tid; t < NBKT; t += 256) table[bid * NBKT + t] = lh[t];
}

// ---------------- bucket totals ----------------
__global__ void k_btot(const int* __restrict__ table, int* __restrict__ btot) {
    int b = blockIdx.x * 256 + threadIdx.x;
    if (b >= NBKT) return;
    int s = 0;
    for (int k = 0; k < NBLK; ++k) s += table[k * NBKT + b];
    btot[b] = s;
}

// ---------------- bucket bases: exclusive scan of btot[391] ----------------
__global__ void k_bbase(const int* __restrict__ btot, int* __restrict__ bktbase) {
    __shared__ int sd[512];
    int tid = threadIdx.x;
    int v = (tid < NBKT) ? btot[tid] : 0;
    sd[tid] = v; __syncthreads();
    int x = v;
    for (int off = 1; off < 512; off <<= 1) {
        int t = (tid >= off) ? sd[tid - off] : 0;
        __syncthreads();
        x += t; sd[tid] = x;
        __syncthreads();
    }
    if (tid < NBKT) bktbase[tid] = x - v;
    if (tid == 0) bktbase[NBKT] = N_EDGES;
}

// ---------------- per-(bucket,block) offsets: goff[block][bkt] ----------------
__global__ void k_goff(const int* __restrict__ table, const int* __restrict__ bktbase,
                       int* __restrict__ goff) {
    __shared__ int sd[NBLK];
    int b = blockIdx.x;           // bucket
    int tid = threadIdx.x;        // block index (128 threads)
    int v = table[tid * NBKT + b];
    sd[tid] = v; __syncthreads();
    int x = v;
    for (int off = 1; off < NBLK; off <<= 1) {
        int t = (tid >= off) ? sd[tid - off] : 0;
        __syncthreads();
        x += t; sd[tid] = x;
        __syncthreads();
    }
    goff[tid * NBKT + b] = bktbase[b] + (x - v);
}

// ---------------- phase C: partition into buckets, single-owner write streams ----------
// entry = slow(8) << 21 | rel(4) << 17 | dst(17)
__global__ __launch_bounds__(256) void k_partB(const int* __restrict__ src,
                                               const int* __restrict__ rel,
                                               const int* __restrict__ dst,
                                               const int* __restrict__ goff,
                                               unsigned int* __restrict__ part) {
    __shared__ int lcur[NBKT];
    int tid = threadIdx.x, bid = blockIdx.x;
    for (int t = tid; t < NBKT; t += 256) lcur[t] = goff[bid * NBKT + t];
    __syncthreads();
    int e0 = bid * EPB;
    for (int e = e0 + tid; e < e0 + EPB; e += 256) {
        int s = src[e];
        int pos = atomicAdd(&lcur[s >> 8], 1);
        part[pos] = ((unsigned)(s & 255) << 21) | ((unsigned)rel[e] << 17) | (unsigned)dst[e];
    }
}

// ---------------- k_place: node-exact placement + offs/cnt/inv2 ----------------
__global__ __launch_bounds__(256) void k_place(const unsigned int* __restrict__ part,
                                               const int* __restrict__ bktbase,
                                               unsigned int* __restrict__ sorted_rd,
                                               int* __restrict__ sorted_src,
                                               int* __restrict__ offs,
                                               int* __restrict__ cnt,
                                               float* __restrict__ inv2) {
    __shared__ int lhist[256 * 16];    // (node-in-bucket, rel) counts
    __shared__ int sd[256];            // scan temp
    __shared__ int lcur[256];          // node cursors
    int b = blockIdx.x, tid = threadIdx.x;
    int n0 = b << 8;
    int base = bktbase[b], end = bktbase[b + 1];
#pragma unroll
    for (int k = 0; k < 16; ++k) lhist[tid + k * 256] = 0;
    __syncthreads();
    for (int t = base + tid; t < end; t += 256)
        atomicAdd(&lhist[part[t] >> 17], 1);   // (slow<<4)|rel, < 4096
    __syncthreads();
    int ncnt = 0;
#pragma unroll
    for (int r = 0; r < 16; ++r) ncnt += lhist[(tid << 4) | r];
    sd[tid] = ncnt; __syncthreads();
    int x = ncnt;
    for (int off = 1; off < 256; off <<= 1) {
        int t = (tid >= off) ? sd[tid - off] : 0;
        __syncthreads();
        x += t; sd[tid] = x;
        __syncthreads();
    }
    int nodeoff = base + (x - ncnt);
    lcur[tid] = nodeoff;
    int node = n0 + tid;
    if (node < N_NODES) { offs[node] = nodeoff; cnt[node] = ncnt; }
    for (int t = tid; t < 4096; t += 256) {
        int nd = n0 + (t >> 4);
        if (nd < N_NODES) {
            int c = lhist[t];
            inv2[((size_t)nd << 4) + (t & 15)] = c ? 1.0f / (float)c : 0.f;
        }
    }
    __syncthreads();
    for (int t = base + tid; t < end; t += 256) {
        unsigned int v = part[t];
        int j = (int)(v >> 21);
        int p = atomicAdd(&lcur[j], 1);
        sorted_rd[p] = v & 0x1FFFFFu;
        if (b < 4) sorted_src[p] = n0 + j;    // buckets 0..3 = nodes 0..1023
    }
}

// ---------------- fused layer-1: aggregate-first + MFMA transform ----------------
// Block = 8 nodes (512 thr, 8 waves; wave w owns node n0+w). Edges contiguous per node.
// LDS agg[2 halves][8 nodes][16 rel][32 emb] f32 — no atomics (per-half copies).
// Then merge*inv -> bf16 aggb[16][520], 2 waves do MFMA (M=16,K=512,N=32), relu'd h1.
__global__ __launch_bounds__(512, 6) void k_l1agg(const unsigned int* __restrict__ sorted_rd,
                                                  const int* __restrict__ offs,
                                                  const int* __restrict__ cnt,
                                                  const float* __restrict__ inv2,
                                                  const unsigned short* __restrict__ embbf,
                                                  const unsigned short* __restrict__ WcatT,
                                                  float* __restrict__ h1) {
    __shared__ float agg[2][8][16][32];      // 32 KB
    __shared__ unsigned short aggb[16][520]; // 16.6 KB (pad 520: row stride 1040B, 16B-aligned)
    int tid = threadIdx.x;
    int w = tid >> 6, lane = tid & 63;
    int n0 = blockIdx.x << 3;
    {   // zero
        float* a = &agg[0][0][0][0];
        for (int t = tid; t < 2 * 8 * 16 * 32; t += 512) a[t] = 0.f;
        unsigned short* bz = &aggb[0][0];
        for (int t = tid; t < 16 * 520; t += 512) bz[t] = 0;
    }
    __syncthreads();
    int n = n0 + w;
    int start = offs[n], ec = cnt[n];
    int h = lane >> 5, i = lane & 31;
    float* myagg = &agg[h][w][0][0];
    // halves interleave groups of 4 edges; 4 gathers in flight per half-wave
    for (int t0 = start + h * 4; t0 < start + ec; t0 += 8) {
        int rem = start + ec - t0;
        unsigned pk0 = sorted_rd[t0];
        unsigned pk1 = (rem > 1) ? sorted_rd[t0 + 1] : 0u;
        unsigned pk2 = (rem > 2) ? sorted_rd[t0 + 2] : 0u;
        unsigned pk3 = (rem > 3) ? sorted_rd[t0 + 3] : 0u;
        float v0 = bf2f(embbf[(size_t)(pk0 & 0x1FFFFu) * 32 + i]);
        float v1 = (rem > 1) ? bf2f(embbf[(size_t)(pk1 & 0x1FFFFu) * 32 + i]) : 0.f;
        float v2 = (rem > 2) ? bf2f(embbf[(size_t)(pk2 & 0x1FFFFu) * 32 + i]) : 0.f;
        float v3 = (rem > 3) ? bf2f(embbf[(size_t)(pk3 & 0x1FFFFu) * 32 + i]) : 0.f;
        myagg[((pk0 >> 17) & 15) * 32 + i] += v0;
        if (rem > 1) myagg[((pk1 >> 17) & 15) * 32 + i] += v1;
        if (rem > 2) myagg[((pk2 >> 17) & 15) * 32 + i] += v2;
        if (rem > 3) myagg[((pk3 >> 17) & 15) * 32 + i] += v3;
    }
    // merge halves + inv scale + bf16 (wave-local: same-wave LDS ordering is in-order)
#pragma unroll
    for (int q = 0; q < 8; ++q) {
        int k = q * 64 + lane;              // 0..511
        int r = k >> 5, j = k & 31;
        float s = (agg[0][w][r][j] + agg[1][w][r][j]) * inv2[((size_t)n << 4) + r];
        aggb[w][k] = f32_to_bf16(s);
    }
    __syncthreads();
    if (w < 2) {   // MFMA: C[16 nodes][32 cols], wave w does cols w*16..+15
        int col16 = lane & 15, kb = lane >> 4;   // kb 0..3
        f32x4 acc = {0.f, 0.f, 0.f, 0.f};
        const unsigned short* wrow = WcatT + (size_t)(w * 16 + col16) * 512;
#pragma unroll
        for (int ks = 0; ks < 16; ++ks) {
            int k0 = ks * 32 + kb * 8;
            short8 a = *(const short8*)&aggb[col16][k0];
            short8 bfr = *(const short8*)&wrow[k0];
            acc = __builtin_amdgcn_mfma_f32_16x16x32_bf16(a, bfr, acc, 0, 0, 0);
        }
#pragma unroll
        for (int reg = 0; reg < 4; ++reg) {
            int row = kb * 4 + reg;              // C row = node-in-block
            if (row < 8)
                h1[(size_t)(n0 + row) * 32 + w * 16 + col16] = fmaxf(acc[reg], 0.f);
        }
    }
}

// ---------------- layer-2 aggregate: agg2[s][r*32+j] += val * h1relu[d][j] ----------------
__global__ void k_agg2(const unsigned int* __restrict__ sorted_rd,
                       const int* __restrict__ sorted_src,
                       const int* __restrict__ offs, const int* __restrict__ cnt,
                       const float* __restrict__ inv2, const float* __restrict__ h1,
                       float* __restrict__ agg2) {
    int E2 = offs[1023] + cnt[1023];
    long total = (long)E2 * 32;
    long stride = (long)gridDim.x * blockDim.x;
    for (long t = (long)blockIdx.x * blockDim.x + threadIdx.x; t < total; t += stride) {
        int e = (int)(t >> 5), j = (int)(t & 31);
        unsigned int pk = sorted_rd[e];
        int r = (int)(pk >> 17), d = (int)(pk & 0x1FFFFu);
        int s = sorted_src[e];
        float val = inv2[((size_t)s << 4) + r];
        atomicAdd(&agg2[(s << 9) + (r << 5) + j], val * h1[d * 32 + j]);
    }
}

// ---------------- layer-2 transform ----------------
__global__ void k_h2(const float* __restrict__ agg2, const float* __restrict__ W2,
                     float* __restrict__ h2pre) {
    int t = blockIdx.x * 256 + threadIdx.x;   // 128 x 256 = 1024*32
    int s = t >> 5, i = t & 31;
    const float* arow = agg2 + (s << 9);
    float acc = 0.f;
#pragma unroll 4
    for (int r = 0; r < 16; ++r) {
        const float* wrow = W2 + r * 1024 + i * 32;
        const float* a = arow + r * 32;
#pragma unroll
        for (int j = 0; j < 32; ++j) acc += wrow[j] * a[j];
    }
    h2pre[t] = acc;
}

// ---------------- classifier ----------------
__global__ void k_cls(const float* __restrict__ h2pre, const float* __restrict__ cls_w,
                      const float* __restrict__ cls_b, float* __restrict__ out) {
    int t = blockIdx.x * 256 + threadIdx.x;
    int b = t >> 6, c = t & 63;
    if (b >= 1024 || c >= 50) return;
    float acc = cls_b[c];
#pragma unroll
    for (int j = 0; j < 32; ++j)
        acc += fmaxf(h2pre[b * 32 + j], 0.f) * cls_w[c * 32 + j];
    out[b * 50 + c] = acc;
}

extern "C" void kernel_launch(void* const* d_in, const int* in_sizes, int n_in,
                              void* d_out, int out_size, void* d_ws, size_t ws_size,
                              hipStream_t stream) {
    const float* emb0  = (const float*)d_in[0];
    const float* W1    = (const float*)d_in[1];
    const float* W2    = (const float*)d_in[2];
    const float* cls_w = (const float*)d_in[3];
    const float* cls_b = (const float*)d_in[4];
    const int*   src   = (const int*)d_in[5];
    const int*   rel   = (const int*)d_in[6];
    const int*   dst   = (const int*)d_in[7];
    float* out = (float*)d_out;

    char* ws = (char*)d_ws;
    size_t off = 0;
    auto alloc = [&](size_t bytes) -> void* {
        void* p = ws + off;
        off = (off + bytes + 255) & ~((size_t)255);
        return p;
    };
    float*          inv2       = (float*)alloc((size_t)N_NODES * 16 * 4);    // 6.4 MB
    int*            offs       = (int*)alloc((size_t)N_NODES * 4);
    int*            cnt        = (int*)alloc((size_t)N_NODES * 4);
    int*            table      = (int*)alloc((size_t)NBLK * NBKT * 4);       // 200 KB
    int*            btot       = (int*)alloc((size_t)NBKT * 4);
    int*            bktbase    = (int*)alloc((size_t)(NBKT + 1) * 4);
    int*            goff       = (int*)alloc((size_t)NBLK * NBKT * 4);       // 200 KB
    unsigned int*   sorted_rd  = (unsigned int*)alloc((size_t)N_EDGES * 4);  // 12.8 MB
    int*            sorted_src = (int*)alloc((size_t)N_EDGES * 4);           // 12.8 MB
    unsigned int*   part       = (unsigned int*)alloc((size_t)N_EDGES * 4);  // 12.8 MB
    unsigned short* embbf      = (unsigned short*)alloc((size_t)N_NODES * 32 * 2); // 6.4 MB
    unsigned short* WcatT      = (unsigned short*)alloc((size_t)32 * 512 * 2);     // 32 KB
    float*          h1         = (float*)alloc((size_t)N_NODES * 32 * 4);    // 12.8 MB
    float*          agg2       = (float*)alloc((size_t)1024 * 512 * 4);      // 2 MB
    float*          h2pre      = (float*)alloc((size_t)1024 * 32 * 4);

    hipMemsetAsync(agg2, 0, (size_t)1024 * 512 * 4, stream);

    k_embcast<<<3125, 256, 0, stream>>>(emb0, embbf);
    k_wcast  <<<1, 512, 0, stream>>>(W1, WcatT);
    k_histA  <<<NBLK, 256, 0, stream>>>(src, table);
    k_btot   <<<2, 256, 0, stream>>>(table, btot);
    k_bbase  <<<1, 512, 0, stream>>>(btot, bktbase);
    k_goff   <<<NBKT, NBLK, 0, stream>>>(table, bktbase, goff);
    k_partB  <<<NBLK, 256, 0, stream>>>(src, rel, dst, goff, part);
    k_place  <<<NBKT, 256, 0, stream>>>(part, bktbase, sorted_rd, sorted_src, offs, cnt, inv2);
    k_l1agg  <<<12500, 512, 0, stream>>>(sorted_rd, offs, cnt, inv2, embbf, WcatT, h1);
    k_agg2   <<<1024, 256, 0, stream>>>(sorted_rd, sorted_src, offs, cnt, inv2, h1, agg2);
    k_h2     <<<128, 256, 0, stream>>>(agg2, W2, h2pre);
    k_cls    <<<256, 256, 0, stream>>>(h2pre, cls_w, cls_b, out);
}